// Round 2
// baseline (121.227 us; speedup 1.0000x reference)
//
#include <hip/hip_runtime.h>
#include <math.h>

#define EPS 1e-6f
constexpr int B    = 64;
constexpr int NC   = 10;
constexpr int ND   = 4;
constexpr int CHW  = 64 * 16 * 16;   // 16384
constexpr int FCHW = 2 * CHW;        // 32768
constexpr int SB   = 32;             // s-values per block in kernel A
constexpr int NBLK_A = CHW / SB;     // 512 blocks
constexpr int NPART  = NBLK_A * 2;   // 1024 half-block partial sets of 20

__device__ __forceinline__ float log_sigmoid(float x) {
    return fminf(x, 0.0f) - log1pf(expf(-fabsf(x)));
}

// Kernel A: fused segment-sum + means/lnm + norm partials.
// Block = 64 threads (1 wave), handles 32 s-values.
// Lane halves split the b-loop (b 0-31 / 32-63), then split nc (0-4 / 5-9).
__global__ void __launch_bounds__(64)
kA(const float* __restrict__ xLE, const int* __restrict__ labels,
   const float* __restrict__ w1, const float* __restrict__ miu,
   const float* __restrict__ tao, const float* __restrict__ sigmas,
   const float* __restrict__ XLEs, const float* __restrict__ Xw,
   float* __restrict__ means_theta, float* __restrict__ lnm,
   float* __restrict__ partials) {
    int tid = threadIdx.x;
    int sl  = tid & 31;
    int bh  = tid >> 5;                  // 0 or 1
    int s   = blockIdx.x * SB + sl;

    // ---- segment sums over my half of b ----
    float a0[NC], a1[NC];
#pragma unroll
    for (int nc = 0; nc < NC; ++nc) { a0[nc] = 0.0f; a1[nc] = 0.0f; }
    int b0 = bh * 32;
#pragma unroll 8
    for (int bb = 0; bb < 32; ++bb) {
        int b   = b0 + bb;
        int lb  = labels[b];
        float v0 = xLE[b * FCHW + s];
        float v1 = xLE[b * FCHW + CHW + s];
#pragma unroll
        for (int nc = 0; nc < NC; ++nc) {
            bool m = (lb == nc);
            a0[nc] += m ? v0 : 0.0f;
            a1[nc] += m ? v1 : 0.0f;
        }
    }
    // combine halves: both halves end with the full sum over b
#pragma unroll
    for (int nc = 0; nc < NC; ++nc) {
        a0[nc] += __shfl_xor(a0[nc], 32, 64);
        a1[nc] += __shfl_xor(a1[nc], 32, 64);
    }

    // ---- label counts (cheap, scalar-ish) ----
    int cint[NC];
#pragma unroll
    for (int nc = 0; nc < NC; ++nc) cint[nc] = 0;
    for (int b = 0; b < B; ++b) {
        int lb = labels[b];
#pragma unroll
        for (int nc = 0; nc < NC; ++nc) cint[nc] += (lb == nc) ? 1 : 0;
    }

    // ---- nd-dependent precompute (hoisted out of nc loop) ----
    float w1sq[ND], s1 = 0.0f;
#pragma unroll
    for (int nd = 0; nd < ND; ++nd) { float t = w1[nd]; w1sq[nd] = t * t; s1 += t * t; }
    float inv_s1 = 1.0f / s1;
    float tao2[ND], m0v[ND], lsm0[ND], lsm1[ND], lsm1e[ND];
#pragma unroll
    for (int nd = 0; nd < ND; ++nd) {
        float tv = tao[nd];
        tao2[nd] = tv * tv;
        float m0 = miu[nd * FCHW + s];
        float m1 = miu[nd * FCHW + CHW + s];
        m0v[nd]  = m0;
        lsm0[nd] = log_sigmoid(m0);
        lsm1[nd] = log_sigmoid(m1);
        lsm1e[nd] = log_sigmoid(m1 + EPS);
    }

    // ---- per-nc compute; my half handles 5 ncs ----
    int ncbase = bh * 5;
    float nacc[ND][5];
#pragma unroll
    for (int j = 0; j < 5; ++j) {
        int nc = ncbase + j;
        float cnt = Xw[nc] + (float)cint[nc];
        float inv_cnt = 1.0f / cnt;
        float sg = sigmas[nc];
        float sig2 = sg * sg;
        float xb0 = (XLEs[nc * FCHW + s] + a0[nc]) * inv_cnt;
        float xb1 = (XLEs[nc * FCHW + CHW + s] + a1[nc]) * inv_cnt;
        float ls0  = log_sigmoid(xb0);
        float ls1  = log_sigmoid(xb1);
        float ls1e = log_sigmoid(xb1 + EPS);
        float theta = 0.0f, magm = 0.0f;
#pragma unroll
        for (int nd = 0; nd < ND; ++nd) {
            float d0 = ls0 - lsm0[nd];
            float d1 = ls1 - lsm1[nd];
            nacc[nd][j] = d0 * d0 + d1 * d1;
            float t2v = tao2[nd];
            float denom = 1.0f / (sig2 + t2v);
            float rt = t2v * denom;
            float rs = sig2 * denom;
            float wn = w1sq[nd] * inv_s1;
            theta += (xb1 * rt + m0v[nd] * rs) * wn;
            magm  += expf((rt * ls1e + rs * lsm1e[nd]) * wn);
        }
        means_theta[nc * CHW + s] = theta;
        lnm[nc * CHW + s] = logf(magm + EPS);
    }

    // ---- reduce nacc over the 32 lanes of my half, write partials ----
#pragma unroll
    for (int nd = 0; nd < ND; ++nd)
#pragma unroll
        for (int j = 0; j < 5; ++j) {
            float v = nacc[nd][j];
            v += __shfl_xor(v, 1, 64);
            v += __shfl_xor(v, 2, 64);
            v += __shfl_xor(v, 4, 64);
            v += __shfl_xor(v, 8, 64);
            v += __shfl_xor(v, 16, 64);
            nacc[nd][j] = v;
        }
    if (sl == 0) {
        float* p = partials + (blockIdx.x * 2 + bh) * 20;
#pragma unroll
        for (int nd = 0; nd < ND; ++nd)
#pragma unroll
            for (int j = 0; j < 5; ++j)
                p[nd * 5 + j] = nacc[nd][j];
    }
}

// Kernel B: x_out over 1M elements; block 0 additionally finalizes loss.
__global__ void __launch_bounds__(256)
kB(const float* __restrict__ xLE, const float* __restrict__ means_theta,
   const float* __restrict__ lnm, const float* __restrict__ weight,
   const float* __restrict__ partials, const int* __restrict__ labels,
   const float* __restrict__ Xw, const float* __restrict__ tao,
   const float* __restrict__ sigmas, float* __restrict__ out) {
    int idx = blockIdx.x * 256 + threadIdx.x;
    int b = idx >> 14;
    int s = idx & (CHW - 1);
    float x0 = xLE[b * FCHW + s];
    float x1 = xLE[b * FCHW + CHW + s];
    float lnx1 = logf(x1);
    float wv0 = weight[0], wv1 = weight[1];
    float w0 = wv0 * wv0, w1s = wv1 * wv1;
    float best = INFINITY;
#pragma unroll
    for (int nc = 0; nc < NC; ++nc) {
        float dr = fabsf(x0 - means_theta[nc * CHW + s]);
        float da = fabsf(lnx1 - lnm[nc * CHW + s]);
        best = fminf(best, w0 * dr + w1s * da);
    }
    out[idx] = best;

    // ---- loss, block 0 only ----
    if (blockIdx.x == 0) {
        __shared__ float term[ND][NC];
        int t = threadIdx.x;
        if (t < ND * NC) {
            int nd = t / NC;
            int nc = t % NC;
            int parity = nc / 5;
            int j = nc % 5;
            float nsum = 0.0f;
            for (int blk = 0; blk < NBLK_A; ++blk)
                nsum += partials[(blk * 2 + parity) * 20 + nd * 5 + j];
            int cint = 0;
            for (int bb = 0; bb < B; ++bb) cint += (labels[bb] == nc) ? 1 : 0;
            float cnt = Xw[nc] + (float)cint;
            float tv = tao[nd];
            float tao2 = tv * tv;
            float sg = sigmas[nc];
            float sig2 = sg * sg;
            float t1 = sig2 / ((tao2 + sig2) * (tao2 + sig2));
            float t2 = sig2 * nsum;
            float t3 = 2.0f * (float)CHW * (tao2 * tao2 - sig2 * sig2) / cnt;
            term[nd][nc] = t1 * (t2 + t3);
        }
        __syncthreads();
        if (t < ND) {
            float acc = 0.0f;
#pragma unroll
            for (int nc = 0; nc < NC; ++nc) acc += term[t][nc];
            out[B * CHW + t] = acc / (float)NC;
        }
    }
}

extern "C" void kernel_launch(void* const* d_in, const int* in_sizes, int n_in,
                              void* d_out, int out_size, void* d_ws, size_t ws_size,
                              hipStream_t stream) {
    const float* xLE    = (const float*)d_in[0];
    const int*   labels = (const int*)  d_in[1];
    const float* w1     = (const float*)d_in[2];
    // d_in[3] (w2) unused: reference derives w2n from w1 (reproduced faithfully).
    const float* miu    = (const float*)d_in[4];
    const float* tao    = (const float*)d_in[5];
    const float* weight = (const float*)d_in[6];
    const float* sigmas = (const float*)d_in[7];
    const float* XLEs   = (const float*)d_in[8];
    const float* Xw     = (const float*)d_in[9];

    float* out = (float*)d_out;                    // x_out [B*CHW] then loss [ND]

    float* means_theta = (float*)d_ws;             // NC*CHW
    float* lnm         = means_theta + NC * CHW;   // NC*CHW
    float* partials    = lnm + NC * CHW;           // NPART*20 = 20480

    kA<<<NBLK_A, 64, 0, stream>>>(xLE, labels, w1, miu, tao, sigmas, XLEs, Xw,
                                  means_theta, lnm, partials);
    kB<<<(B * CHW) / 256, 256, 0, stream>>>(xLE, means_theta, lnm, weight,
                                            partials, labels, Xw, tao, sigmas, out);
}

// Round 5
// 120.781 us; speedup vs baseline: 1.0037x; 1.0037x over previous
//
#include <hip/hip_runtime.h>
#include <math.h>

#define EPS 1e-6f
constexpr int B    = 64;
constexpr int NC   = 10;
constexpr int ND   = 4;
constexpr int CHW  = 64 * 16 * 16;   // 16384
constexpr int FCHW = 2 * CHW;        // 32768
constexpr int SB   = 32;             // s-values per block in kernel A
constexpr int NBLK_A = CHW / SB;     // 512 blocks
constexpr int NPART  = NBLK_A * 2;   // 1024 half-block partial sets of 20

__device__ __forceinline__ float log_sigmoid(float x) {
    return fminf(x, 0.0f) - log1pf(expf(-fabsf(x)));
}

// Kernel A: fused segment-sum + means/lnm + norm partials.
// Block = 64 threads (1 wave), handles 32 s-values.
// Lane halves split the b-loop (b 0-31 / 32-63), then split nc (0-4 / 5-9).
__global__ void __launch_bounds__(64)
kA(const float* __restrict__ xLE, const int* __restrict__ labels,
   const float* __restrict__ w1, const float* __restrict__ miu,
   const float* __restrict__ tao, const float* __restrict__ sigmas,
   const float* __restrict__ XLEs, const float* __restrict__ Xw,
   float* __restrict__ means_theta, float* __restrict__ lnm,
   float* __restrict__ partials) {
    int tid = threadIdx.x;
    int sl  = tid & 31;
    int bh  = tid >> 5;                  // 0 or 1
    int s   = blockIdx.x * SB + sl;

    // ---- segment sums over my half of b ----
    float a0[NC], a1[NC];
#pragma unroll
    for (int nc = 0; nc < NC; ++nc) { a0[nc] = 0.0f; a1[nc] = 0.0f; }
    int b0 = bh * 32;
#pragma unroll 8
    for (int bb = 0; bb < 32; ++bb) {
        int b   = b0 + bb;
        int lb  = labels[b];
        float v0 = xLE[b * FCHW + s];
        float v1 = xLE[b * FCHW + CHW + s];
#pragma unroll
        for (int nc = 0; nc < NC; ++nc) {
            bool m = (lb == nc);
            a0[nc] += m ? v0 : 0.0f;
            a1[nc] += m ? v1 : 0.0f;
        }
    }
    // combine halves: both halves end with the full sum over b
#pragma unroll
    for (int nc = 0; nc < NC; ++nc) {
        a0[nc] += __shfl_xor(a0[nc], 32, 64);
        a1[nc] += __shfl_xor(a1[nc], 32, 64);
    }

    // ---- label counts (cheap, scalar-ish) ----
    int cint[NC];
#pragma unroll
    for (int nc = 0; nc < NC; ++nc) cint[nc] = 0;
    for (int b = 0; b < B; ++b) {
        int lb = labels[b];
#pragma unroll
        for (int nc = 0; nc < NC; ++nc) cint[nc] += (lb == nc) ? 1 : 0;
    }

    // ---- nd-dependent precompute (hoisted out of nc loop) ----
    float w1sq[ND], s1 = 0.0f;
#pragma unroll
    for (int nd = 0; nd < ND; ++nd) { float t = w1[nd]; w1sq[nd] = t * t; s1 += t * t; }
    float inv_s1 = 1.0f / s1;
    float tao2[ND], m0v[ND], lsm0[ND], lsm1[ND], lsm1e[ND];
#pragma unroll
    for (int nd = 0; nd < ND; ++nd) {
        float tv = tao[nd];
        tao2[nd] = tv * tv;
        float m0 = miu[nd * FCHW + s];
        float m1 = miu[nd * FCHW + CHW + s];
        m0v[nd]  = m0;
        lsm0[nd] = log_sigmoid(m0);
        lsm1[nd] = log_sigmoid(m1);
        lsm1e[nd] = log_sigmoid(m1 + EPS);
    }

    // ---- per-nc compute; my half handles 5 ncs ----
    int ncbase = bh * 5;
    float nacc[ND][5];
#pragma unroll
    for (int j = 0; j < 5; ++j) {
        int nc = ncbase + j;
        float cnt = Xw[nc] + (float)cint[nc];
        float inv_cnt = 1.0f / cnt;
        float sg = sigmas[nc];
        float sig2 = sg * sg;
        float xb0 = (XLEs[nc * FCHW + s] + a0[nc]) * inv_cnt;
        float xb1 = (XLEs[nc * FCHW + CHW + s] + a1[nc]) * inv_cnt;
        float ls0  = log_sigmoid(xb0);
        float ls1  = log_sigmoid(xb1);
        float ls1e = log_sigmoid(xb1 + EPS);
        float theta = 0.0f, magm = 0.0f;
#pragma unroll
        for (int nd = 0; nd < ND; ++nd) {
            float d0 = ls0 - lsm0[nd];
            float d1 = ls1 - lsm1[nd];
            nacc[nd][j] = d0 * d0 + d1 * d1;
            float t2v = tao2[nd];
            float denom = 1.0f / (sig2 + t2v);
            float rt = t2v * denom;
            float rs = sig2 * denom;
            float wn = w1sq[nd] * inv_s1;
            theta += (xb1 * rt + m0v[nd] * rs) * wn;
            magm  += expf((rt * ls1e + rs * lsm1e[nd]) * wn);
        }
        means_theta[nc * CHW + s] = theta;
        lnm[nc * CHW + s] = logf(magm + EPS);
    }

    // ---- reduce nacc over the 32 lanes of my half, write partials ----
#pragma unroll
    for (int nd = 0; nd < ND; ++nd)
#pragma unroll
        for (int j = 0; j < 5; ++j) {
            float v = nacc[nd][j];
            v += __shfl_xor(v, 1, 64);
            v += __shfl_xor(v, 2, 64);
            v += __shfl_xor(v, 4, 64);
            v += __shfl_xor(v, 8, 64);
            v += __shfl_xor(v, 16, 64);
            nacc[nd][j] = v;
        }
    if (sl == 0) {
        float* p = partials + (blockIdx.x * 2 + bh) * 20;
#pragma unroll
        for (int nd = 0; nd < ND; ++nd)
#pragma unroll
            for (int j = 0; j < 5; ++j)
                p[nd * 5 + j] = nacc[nd][j];
    }
}

// Kernel B: x_out over 1M elements; block 0 additionally finalizes loss.
__global__ void __launch_bounds__(256)
kB(const float* __restrict__ xLE, const float* __restrict__ means_theta,
   const float* __restrict__ lnm, const float* __restrict__ weight,
   const float* __restrict__ partials, const int* __restrict__ labels,
   const float* __restrict__ Xw, const float* __restrict__ tao,
   const float* __restrict__ sigmas, float* __restrict__ out) {
    int idx = blockIdx.x * 256 + threadIdx.x;
    int b = idx >> 14;
    int s = idx & (CHW - 1);
    float x0 = xLE[b * FCHW + s];
    float x1 = xLE[b * FCHW + CHW + s];
    float lnx1 = logf(x1);
    float wv0 = weight[0], wv1 = weight[1];
    float w0 = wv0 * wv0, w1s = wv1 * wv1;
    float best = INFINITY;
#pragma unroll
    for (int nc = 0; nc < NC; ++nc) {
        float dr = fabsf(x0 - means_theta[nc * CHW + s]);
        float da = fabsf(lnx1 - lnm[nc * CHW + s]);
        best = fminf(best, w0 * dr + w1s * da);
    }
    out[idx] = best;

    // ---- loss, block 0 only ----
    if (blockIdx.x == 0) {
        __shared__ float term[ND][NC];
        int t = threadIdx.x;
        if (t < ND * NC) {
            int nd = t / NC;
            int nc = t % NC;
            int parity = nc / 5;
            int j = nc % 5;
            float nsum = 0.0f;
            for (int blk = 0; blk < NBLK_A; ++blk)
                nsum += partials[(blk * 2 + parity) * 20 + nd * 5 + j];
            int cint = 0;
            for (int bb = 0; bb < B; ++bb) cint += (labels[bb] == nc) ? 1 : 0;
            float cnt = Xw[nc] + (float)cint;
            float tv = tao[nd];
            float tao2 = tv * tv;
            float sg = sigmas[nc];
            float sig2 = sg * sg;
            float t1 = sig2 / ((tao2 + sig2) * (tao2 + sig2));
            float t2 = sig2 * nsum;
            float t3 = 2.0f * (float)CHW * (tao2 * tao2 - sig2 * sig2) / cnt;
            term[nd][nc] = t1 * (t2 + t3);
        }
        __syncthreads();
        if (t < ND) {
            float acc = 0.0f;
#pragma unroll
            for (int nc = 0; nc < NC; ++nc) acc += term[t][nc];
            out[B * CHW + t] = acc / (float)NC;
        }
    }
}

extern "C" void kernel_launch(void* const* d_in, const int* in_sizes, int n_in,
                              void* d_out, int out_size, void* d_ws, size_t ws_size,
                              hipStream_t stream) {
    const float* xLE    = (const float*)d_in[0];
    const int*   labels = (const int*)  d_in[1];
    const float* w1     = (const float*)d_in[2];
    // d_in[3] (w2) unused: reference derives w2n from w1 (reproduced faithfully).
    const float* miu    = (const float*)d_in[4];
    const float* tao    = (const float*)d_in[5];
    const float* weight = (const float*)d_in[6];
    const float* sigmas = (const float*)d_in[7];
    const float* XLEs   = (const float*)d_in[8];
    const float* Xw     = (const float*)d_in[9];

    float* out = (float*)d_out;                    // x_out [B*CHW] then loss [ND]

    float* means_theta = (float*)d_ws;             // NC*CHW
    float* lnm         = means_theta + NC * CHW;   // NC*CHW
    float* partials    = lnm + NC * CHW;           // NPART*20 = 20480

    kA<<<NBLK_A, 64, 0, stream>>>(xLE, labels, w1, miu, tao, sigmas, XLEs, Xw,
                                  means_theta, lnm, partials);
    kB<<<(B * CHW) / 256, 256, 0, stream>>>(xLE, means_theta, lnm, weight,
                                            partials, labels, Xw, tao, sigmas, out);
}